// Round 6
// baseline (107.298 us; speedup 1.0000x reference)
//
#include <hip/hip_runtime.h>
#include <hip/hip_bf16.h>
#include <cstdint>

// Problem constants (reference: BATCH=4096, N_VIEWS=2, T=0.07, D=128 -> N=8192)
#define NROWS 8192
#define FDIM  128
#define HALF_N 4096

typedef short bf16x8 __attribute__((ext_vector_type(8)));   // 8 bf16 = 4 VGPRs
typedef float f32x4  __attribute__((ext_vector_type(4)));

// k1 = log2(e)/T so exp((s-1)/T) = exp2(k1*s - k1)
#define K1 (1.4426950408889634f / 0.07f)

#if __has_builtin(__builtin_amdgcn_exp2f)
#define EXP2(x) __builtin_amdgcn_exp2f(x)       // raw v_exp_f32
#else
#define EXP2(x) exp2f(x)
#endif

// Fragment-packed layout of the normalized bf16 matrix:
//   frag (rb, ks) at flat bf16x8 index (rb*4+ks)*64 + lane,
//   lane = quad*16 + (r&15) holds row r = rb*16+(lane&15), k = ks*32+quad*8..+8.
// One coalesced global_load_dwordx4 per fragment. 2 MB total.

// ---------------------------------------------------------------------------
// Kernel 1: L2-normalize rows (fp32, matching ref), write fragment-packed
// bf16. Also zero-inits esum_g.
// ---------------------------------------------------------------------------
__global__ void __launch_bounds__(256) normalize_kernel(const float* __restrict__ f,
                                                        short* __restrict__ packed,
                                                        float* __restrict__ esum_g) {
    const int row  = blockIdx.x * 4 + (threadIdx.x >> 6);
    const int lane = threadIdx.x & 63;           // element k = 2*lane, 2*lane+1
    const float2 v = ((const float2*)(f + (size_t)row * FDIM))[lane];
    float ss = v.x * v.x + v.y * v.y;
    #pragma unroll
    for (int m = 1; m < 64; m <<= 1) ss += __shfl_xor(ss, m);
    const float scale = 1.0f / fmaxf(sqrtf(ss), 1e-12f);

    const int off = ((((row >> 4) * 4 + (lane >> 4)) * 64)
                     + ((lane >> 2) & 3) * 16 + (row & 15)) * 8 + 2 * (lane & 3);
    __hip_bfloat16 b0 = __float2bfloat16(v.x * scale);
    __hip_bfloat16 b1 = __float2bfloat16(v.y * scale);
    unsigned u = (unsigned)*(unsigned short*)&b0
               | ((unsigned)*(unsigned short*)&b1 << 16);
    *(unsigned*)(packed + off) = u;              // 4B-aligned (off is even)

    if (threadIdx.x < 4) esum_g[blockIdx.x * 4 + threadIdx.x] = 0.0f;
}

__device__ __forceinline__ float2 bf2_to_f2(unsigned u) {
    return make_float2(__uint_as_float(u << 16),
                       __uint_as_float(u & 0xffff0000u));
}

// ---------------------------------------------------------------------------
// Kernel 2: SYMMETRIC fused sim+exp+rowsum (half the tiles of rounds 0-5).
// 128 row-strips of 64. Strip i needs bands d = 0..64 (tile (i, (i+d)&127)):
//   d=1..63 : row-sums -> esum[strip i], col-sums -> esum[strip (i+d)&127]
//             (exp(sim) symmetric; col-sum of tile (i,j) = mirrored row-sum)
//   d=0, 64 : row-sums only (d=0 full square; d=64 appears in both
//             orientations as i sweeps 0..127)
// cb unit = (d, fc): 16 cols x 64 rows x K=128 = 16 MFMA. Per strip: 260 cbs
// (65 d x 4 fc, d-major). Wave (i, c), c=0..15 handles p = c, c+16, ... —
// 17-stage fully-unrolled pipeline, prefetch distance 2, 3 static buffers.
// Block's 4 waves: same d, fc=0..3 -> contiguous 16 KB B-tile per step.
// Blocks 512..543: pos_i = <f_i, f_(i^4096)>, diag_i = exp((<f_i,f_i>-1)/T).
// ---------------------------------------------------------------------------
__global__ void __launch_bounds__(256, 2) sim_kernel(const short* __restrict__ pk,
                                                     float* __restrict__ esum_g,
                                                     float* __restrict__ pos_g,
                                                     float* __restrict__ diag_g) {
    if (blockIdx.x >= 512) {
        // ---- pos/diag path: one thread per row ----
        const int i  = (blockIdx.x - 512) * 256 + threadIdx.x;
        const int ip = i ^ HALF_N;
        const uint4* P = (const uint4*)pk;
        float dot = 0.f, self = 0.f;
        #pragma unroll
        for (int cc = 0; cc < 16; cc++) {        // cc = ks*4 + quad
            const uint4 a = P[((i  >> 4) * 4 + (cc >> 2)) * 64 + (cc & 3) * 16 + (i  & 15)];
            const uint4 b = P[((ip >> 4) * 4 + (cc >> 2)) * 64 + (cc & 3) * 16 + (ip & 15)];
            const unsigned au[4] = {a.x, a.y, a.z, a.w};
            const unsigned bu[4] = {b.x, b.y, b.z, b.w};
            #pragma unroll
            for (int q = 0; q < 4; q++) {
                const float2 av = bf2_to_f2(au[q]);
                const float2 bv = bf2_to_f2(bu[q]);
                dot  = __builtin_fmaf(av.x, bv.x, __builtin_fmaf(av.y, bv.y, dot));
                self = __builtin_fmaf(av.x, av.x, __builtin_fmaf(av.y, av.y, self));
            }
        }
        pos_g[i]  = dot;
        diag_g[i] = EXP2(__builtin_fmaf(self, K1, -K1));
        return;
    }

    const int tid   = threadIdx.x;
    const int w     = tid >> 6;
    const int lane  = tid & 63;
    const int quad  = lane >> 4;
    const int l16   = lane & 15;
    const int strip = blockIdx.x >> 2;           // 0..127
    const int c     = (blockIdx.x & 3) * 4 + w;  // 0..15
    const bf16x8* P = (const bf16x8*)pk;

    // A fragments for this wave's 64 rows (strip), parked: a_reg[ks][fr]
    bf16x8 a_reg[4][4];
    #pragma unroll
    for (int fr = 0; fr < 4; fr++)
        #pragma unroll
        for (int ks = 0; ks < 4; ks++)
            a_reg[ks][fr] = P[((strip * 4 + fr) * 4 + ks) * 64 + lane];

    float ep[4][4];                              // [fr][r] row partials
    #pragma unroll
    for (int a = 0; a < 4; a++)
        #pragma unroll
        for (int b = 0; b < 4; b++) ep[a][b] = 0.0f;

    // cb p -> flat bf16x8 base (ks advances by 64): clamp invalid p to c.
    auto cb_clamp = [&](int p) { return (p < 260) ? p : c; };
    auto cb_base  = [&](int p) {
        const int d = p >> 2, fc = p & 3;
        const int js = (strip + d) & 127;
        return ((js * 4 + fc) * 4) * 64 + lane;
    };

    bf16x8 bbuf[3][4];
    {
        const int b0 = cb_base(cb_clamp(c));
        const int b1 = cb_base(cb_clamp(c + 16));
        #pragma unroll
        for (int ks = 0; ks < 4; ks++) {
            bbuf[0][ks] = P[b0 + ks * 64];
            bbuf[1][ks] = P[b1 + ks * 64];
        }
    }

    #pragma unroll
    for (int k = 0; k < 17; k++) {
        // prefetch cb(k+2) into slot (k+2)%3
        if (k + 2 < 17) {
            const int bn = cb_base(cb_clamp(c + 16 * (k + 2)));
            #pragma unroll
            for (int ks = 0; ks < 4; ks++)
                bbuf[(k + 2) % 3][ks] = P[bn + ks * 64];
        }
        const int p = c + 16 * k;
        if (p < 260) {                           // wave-uniform guard
            const int d  = p >> 2, fc = p & 3;
            const int js = (strip + d) & 127;

            f32x4 acc[4];
            #pragma unroll
            for (int fr = 0; fr < 4; fr++) acc[fr] = (f32x4){0.f, 0.f, 0.f, 0.f};
            #pragma unroll
            for (int ks = 0; ks < 4; ks++)
                #pragma unroll
                for (int fr = 0; fr < 4; fr++)
                    acc[fr] = __builtin_amdgcn_mfma_f32_16x16x32_bf16(
                                  a_reg[ks][fr], bbuf[k % 3][ks], acc[fr], 0, 0, 0);

            // e = exp((s-1)/T); row partials always, col-sum for d=1..63
            float cs = 0.0f;
            #pragma unroll
            for (int fr = 0; fr < 4; fr++)
                #pragma unroll
                for (int r = 0; r < 4; r++) {
                    const float e = EXP2(__builtin_fmaf(acc[fr][r], K1, -K1));
                    ep[fr][r] += e;
                    cs += e;
                }
            if (d != 0 && d != 64) {             // wave-uniform
                cs += __shfl_xor(cs, 16);
                cs += __shfl_xor(cs, 32);        // all lanes: 64-row col sum
                if (lane < 16)
                    atomicAdd(&esum_g[js * 64 + fc * 16 + lane], cs);
            }
        }
    }

    // reduce row partials across the 16 column-lanes, commit once per wave
    #pragma unroll
    for (int fr = 0; fr < 4; fr++)
        #pragma unroll
        for (int r = 0; r < 4; r++) {
            float v = ep[fr][r];
            #pragma unroll
            for (int m = 1; m < 16; m <<= 1) v += __shfl_xor(v, m);
            if (l16 == 0)
                atomicAdd(&esum_g[strip * 64 + fr * 16 + quad * 4 + r], v);
        }
}

// ---------------------------------------------------------------------------
// Kernel 3: loss_i = ln(esum_i - diag_i) + 1/T - pos_i/T ; out = mean(loss).
// ---------------------------------------------------------------------------
__global__ void __launch_bounds__(256) final_kernel(const float* __restrict__ esum_g,
                                                    const float* __restrict__ pos_g,
                                                    const float* __restrict__ diag_g,
                                                    float* __restrict__ out) {
    const int tid = threadIdx.x;
    const float invT = 1.0f / 0.07f;
    float acc = 0.0f;
    for (int i = tid; i < NROWS; i += 256)
        acc += logf(esum_g[i] - diag_g[i]) + invT - pos_g[i] * invT;
    #pragma unroll
    for (int m = 1; m < 64; m <<= 1) acc += __shfl_xor(acc, m);
    __shared__ float ws[4];
    if ((tid & 63) == 0) ws[tid >> 6] = acc;
    __syncthreads();
    if (tid == 0) out[0] = (ws[0] + ws[1] + ws[2] + ws[3]) * (1.0f / (float)NROWS);
}

// ---------------------------------------------------------------------------
extern "C" void kernel_launch(void* const* d_in, const int* in_sizes, int n_in,
                              void* d_out, int out_size, void* d_ws, size_t ws_size,
                              hipStream_t stream) {
    const float* features = (const float*)d_in[0];
    float* out = (float*)d_out;

    char* ws = (char*)d_ws;
    short* packed = (short*)ws;                                          // 2 MB
    float* esum_g = (float*)(ws + (size_t)NROWS * FDIM * 2);             // 32 KB
    float* pos_g  = (float*)(ws + (size_t)NROWS * FDIM * 2 + NROWS * 4); // 32 KB
    float* diag_g = (float*)(ws + (size_t)NROWS * FDIM * 2 + NROWS * 8); // 32 KB

    normalize_kernel<<<NROWS / 4, 256, 0, stream>>>(features, packed, esum_g);

    sim_kernel<<<512 + NROWS / 256, 256, 0, stream>>>(packed, esum_g, pos_g, diag_g);

    final_kernel<<<1, 256, 0, stream>>>(esum_g, pos_g, diag_g, out);
}